// Round 3
// baseline (110.274 us; speedup 1.0000x reference)
//
#include <hip/hip_runtime.h>
#include <hip/hip_bf16.h>
#include <math.h>

// SSD post-processing for MI355X.
// (1) fused softmax + transpose + per-(b,c) histogram (scores written once,
//     hist built from registers -> saves the 44 MB hist read);
// (2) per-(b,c) top-200: parallel-suffix-scan threshold + collect + bitonic;
// (3) NMS: fused gather/decode + merge-rank sort -> parallel IoU bitmask ->
//     single-wave pipelined serial reduce with EARLY EXIT at 200 keeps.
//
// R14: hipMemsetAsync(ghist) replaced with a custom zero kernel. rocprof
// showed the runtime's fillBufferAligned taking ~40 us for the 1.8 MB ghist
// clear (45 GB/s, 8% occupancy) at the HEAD of the dependency chain — 36%
// of total runtime. A 448-block uint4 store kernel does it in ~2 us.

#define NCLS 8
#define NFG 7
#define TOPK 200
#define NMSM (NFG * TOPK)   // 1400
#define NCH 22              // ceil(1400/64) 64-wide chunks
#define NPAIRS (NCH * (NCH + 1) / 2)  // 253 upper-triangle chunk pairs
#define BROWS 64
#define BWORDS (BROWS * NCH)          // 1408 u64 per 64-row mask block
#define NRND 11                       // 1 KB global_load_lds rounds per block
#define NBUF 4                        // LDS ring slots (lead=2, reuse dist 4)
#define HSLICE 16                     // image slices for fused score+hist
#define LOW_SCORE 0.01f
#define NMS_THR 0.45f
#define BINS 2048                     // bits>>19 of score<1.0 is <= 2031
#define CAP 4096

// ---------------- stage 0: zero the global histogram ----------------
// 224*2048 u32 = 1.8 MB. hipMemsetAsync's fillBufferAligned took ~40 us for
// this (rocprof R13: WRITE_SIZE=1792KB, 45 GB/s); this kernel is ~2 us.
__global__ __launch_bounds__(256) void zero_hist_kernel(uint4* __restrict__ p,
                                                        int n16) {
  int i = blockIdx.x * 256 + threadIdx.x;
  if (i < n16) p[i] = make_uint4(0u, 0u, 0u, 0u);
}

// ---------------- stage 1: fused softmax + transpose + histogram ----------
// Grid (HSLICE, B), 1024 threads. Each block: one image slice of A/HSLICE
// anchors. Softmax values go to scores[] (transposed [b][c][a]) AND to a
// 7-row LDS histogram (57 KB -> 2 blocks/CU), flushed with global atomics.
__global__ __launch_bounds__(1024) void score_hist_kernel(
    const float* __restrict__ logits, float* __restrict__ scores,
    unsigned* __restrict__ ghist, int A) {
  __shared__ unsigned hist[NFG * BINS];   // 7*2048*4 = 57344 B
  int tid = threadIdx.x;
  int b = blockIdx.y;
  int slice = blockIdx.x;
  int sl = A / HSLICE;                    // 3066
  for (int i = tid; i < NFG * BINS; i += 1024) hist[i] = 0;
  __syncthreads();

  int a0 = slice * sl;
  for (int k = tid; k < sl; k += 1024) {
    int a = a0 + k;
    const float4* p4 = (const float4*)(logits + ((size_t)b * A + a) * NCLS);
    float4 v0 = p4[0], v1 = p4[1];
    float x[NCLS] = {v0.x, v0.y, v0.z, v0.w, v1.x, v1.y, v1.z, v1.w};
    float mx = x[0];
#pragma unroll
    for (int c = 1; c < NCLS; c++) mx = fmaxf(mx, x[c]);
    float e[NCLS];
    float s = 0.0f;
#pragma unroll
    for (int c = 0; c < NCLS; c++) { e[c] = expf(x[c] - mx); s += e[c]; }
    float inv = 1.0f / s;
#pragma unroll
    for (int c = 1; c < NCLS; c++) {
      float v = e[c] * inv;
      scores[((size_t)b * NFG + (c - 1)) * A + a] = v;
      atomicAdd(&hist[(c - 1) * BINS + (__float_as_uint(v) >> 19)], 1u);
    }
  }
  __syncthreads();

  unsigned* g = ghist + (size_t)b * NFG * BINS;
  for (int i = tid; i < NFG * BINS; i += 1024) {
    unsigned v = hist[i];
    if (v) atomicAdd(&g[i], v);
  }
}

// ---------------- bitonic sort (descending) on shared ulong ----------------
__device__ inline void bitonic_desc(unsigned long long* buf, int P, int tid, int nthr) {
  for (int k = 2; k <= P; k <<= 1) {
    for (int j = k >> 1; j > 0; j >>= 1) {
      __syncthreads();
      for (int i = tid; i < P; i += nthr) {
        int l = i ^ j;
        if (l > i) {
          unsigned long long va = buf[i], vb = buf[l];
          bool descRegion = ((i & k) == 0);
          if (descRegion ? (va < vb) : (va > vb)) { buf[i] = vb; buf[l] = va; }
        }
      }
    }
  }
  __syncthreads();
}

// ---------------- stage 2: select threshold + collect + sort ----------------
// 1024 threads (grid pinned at 224 blocks; block size is the occupancy
// lever). Suffix scan stays 256-wide (tid<256 guards on the WORK, all
// threads hit every barrier).
__global__ __launch_bounds__(1024) void select_kernel(
    const float* __restrict__ scores, const unsigned* __restrict__ ghist, int A,
    float* __restrict__ tval, int* __restrict__ tidx) {
  __shared__ unsigned long long buf[CAP];
  __shared__ int sfx[256];
  __shared__ int s_t, s_cnt;
  int tid = threadIdx.x;
  int row = blockIdx.x;  // b*7 + c
  const unsigned* h = ghist + (size_t)row * BINS;
  if (tid == 0) s_cnt = 0;

  // per-thread 8-bin sums, then 8-step suffix scan: sfx[g] = sum bins >= g*8
  if (tid < 256) {
    int s = 0;
#pragma unroll
    for (int k = 0; k < 8; k++) s += (int)h[tid * 8 + k];
    sfx[tid] = s;
  }
  __syncthreads();
  for (int off = 1; off < 256; off <<= 1) {
    int v = 0;
    if (tid < 256) v = sfx[tid] + ((tid + off < 256) ? sfx[tid + off] : 0);
    __syncthreads();
    if (tid < 256) sfx[tid] = v;
    __syncthreads();
  }
  // find group g* = max g with sfx[g] >= TOPK, refine within its 8 bins
  if (tid < 256) {
    if (sfx[0] < TOPK) {
      if (tid == 0) s_t = 0;
    } else {
      bool mine = (sfx[tid] >= TOPK) && (tid == 255 || sfx[tid + 1] < TOPK);
      if (mine) {
        int cum = (tid == 255) ? 0 : sfx[tid + 1];
        int t = tid * 8 + 7;
        for (; t >= tid * 8; t--) { cum += (int)h[t]; if (cum >= TOPK) break; }
        s_t = t;
      }
    }
  }
  __syncthreads();

  // collect candidates (bin >= threshold) with float4 loads
  unsigned tbin = (unsigned)s_t;
  const float4* p4 = (const float4*)(scores + (size_t)row * A);
  int n4 = A / 4;
  for (int k = tid; k < n4; k += 1024) {
    float4 v = p4[k];
    float c4[4] = {v.x, v.y, v.z, v.w};
#pragma unroll
    for (int j = 0; j < 4; j++) {
      unsigned key = __float_as_uint(c4[j]);
      if ((key >> 19) >= tbin) {
        int pos = atomicAdd(&s_cnt, 1);
        if (pos < CAP)
          buf[pos] = ((unsigned long long)key << 32) | (unsigned)(~(4 * k + j));
      }
    }
  }
  __syncthreads();
  int cnt = s_cnt; if (cnt > CAP) cnt = CAP;
  int P = 256; while (P < cnt) P <<= 1;
  for (int i = cnt + tid; i < P; i += 1024) buf[i] = 0ull;
  __syncthreads();
  bitonic_desc(buf, P, tid, 1024);
  if (tid < TOPK) {
    unsigned long long v = buf[tid];
    tval[(size_t)row * TOPK + tid] = __uint_as_float((unsigned)(v >> 32));
    tidx[(size_t)row * TOPK + tid] = (int)(~(unsigned)(v & 0xFFFFFFFFull));
  }
}

// ---------------- stage 3: fused gather/decode + per-image merge-rank sort --
// The 1400 candidates are 7 per-class lists, each STRICTLY DESCENDING in the
// composite key (score_bits<<32)|~m. Global sorted position = sum over the 7
// lists of count(key > key_e); own list contributes exactly r. 7 independent
// unrolled binary searches per element (ILP hides LDS latency).
// Decode happens here (was a separate gather kernel); cboxes/cscores are
// still written to global for nms_serial's output stage.
__global__ __launch_bounds__(1024) void nms_sort_kernel(
    const float* __restrict__ deltas, const float* __restrict__ dbox,
    const float* __restrict__ tval, const int* __restrict__ tidx,
    float* __restrict__ cboxes, float* __restrict__ cscores,
    float* __restrict__ sx0, float* __restrict__ sy0,
    float* __restrict__ sx1, float* __restrict__ sy1,
    float* __restrict__ sar, int* __restrict__ sord, int* __restrict__ nvalid,
    int A) {
  __shared__ unsigned long long keys[NMSM];
  __shared__ float bx0[NMSM], by0[NMSM], bx1[NMSM], by1[NMSM];
  __shared__ int s_cnt;
  int tid = threadIdx.x;
  int b = blockIdx.x;
  if (tid == 0) s_cnt = 0;
  __syncthreads();

  int myv = 0;
  for (int m = tid; m < NMSM; m += 1024) {
    int c = m / TOPK;
    int r = m - c * TOPK;
    size_t tk = ((size_t)b * NFG + c) * TOPK + r;
    int a = tidx[tk];
    float v = tval[tk];
    // decode
    const float* db = dbox + (size_t)a * 4;
    float w = db[2] - db[0];
    float h = db[3] - db[1];
    float cx = db[0] + 0.5f * w;
    float cy = db[1] + 0.5f * h;
    const float* dd = deltas + ((size_t)b * A + a) * 4;
    float pcx = dd[0] / 10.0f * w + cx;
    float pcy = dd[1] / 10.0f * h + cy;
    float pw = expf(dd[2] / 5.0f) * w;
    float ph = expf(dd[3] / 5.0f) * h;
    float x0 = fminf(fmaxf(pcx - 0.5f * pw, 0.0f), 1.0f);
    float y0 = fminf(fmaxf(pcy - 0.5f * ph, 0.0f), 1.0f);
    float x1 = fminf(fmaxf(pcx + 0.5f * pw, 0.0f), 1.0f);
    float y1 = fminf(fmaxf(pcy + 0.5f * ph, 0.0f), 1.0f);
    size_t gi = (size_t)b * NMSM + m;
    float* cb = cboxes + gi * 4;
    cb[0] = x0; cb[1] = y0; cb[2] = x1; cb[3] = y1;
    cscores[gi] = v;
    bx0[m] = x0; by0[m] = y0; bx1[m] = x1; by1[m] = y1;
    unsigned k32 = (v > LOW_SCORE) ? __float_as_uint(v) : 0u;
    if (k32) myv++;
    keys[m] = ((unsigned long long)k32 << 32) | (unsigned)(~m);
  }
  if (myv) atomicAdd(&s_cnt, myv);
  __syncthreads();

  size_t base = (size_t)b * NMSM;
  for (int m = tid; m < NMSM; m += 1024) {
    unsigned long long k = keys[m];
    int c = m / TOPK;
    int lo[NFG], hi[NFG];
#pragma unroll
    for (int cc = 0; cc < NFG; cc++) { lo[cc] = 0; hi[cc] = TOPK; }
#pragma unroll
    for (int s8 = 0; s8 < 8; s8++) {
#pragma unroll
      for (int cc = 0; cc < NFG; cc++) {
        if (lo[cc] < hi[cc]) {
          int mid = (lo[cc] + hi[cc]) >> 1;
          if (keys[cc * TOPK + mid] > k) lo[cc] = mid + 1; else hi[cc] = mid;
        }
      }
    }
    int p = 0;
#pragma unroll
    for (int cc = 0; cc < NFG; cc++) p += lo[cc];

    float off = 4.0f * (float)(c + 1);
    float x0 = bx0[m] + off, y0 = by0[m] + off;
    float x1 = bx1[m] + off, y1 = by1[m] + off;
    sord[base + p] = m;
    sx0[base + p] = x0; sy0[base + p] = y0;
    sx1[base + p] = x1; sy1[base + p] = y1;
    sar[base + p] = (x1 - x0) * (y1 - y0);
  }
  if (tid == 0) nvalid[b] = s_cnt;
}

// ---------------- stage 4a: suppression bitmask ----------------
// NOTE: only upper-triangle chunk pairs (cj >= ci) are WRITTEN. Words cj < ci
// of a mask row are never initialized (0xAA poison) — consumers MUST NOT
// apply them (wmask in nms_serial_kernel; this broke Round 3).
__global__ __launch_bounds__(64) void nms_mask_kernel(
    const float* __restrict__ sx0, const float* __restrict__ sy0,
    const float* __restrict__ sx1, const float* __restrict__ sy1,
    const float* __restrict__ sar, unsigned long long* __restrict__ mask) {
  int b = blockIdx.y;
  int pair = blockIdx.x;
  int ci = 0, rem = pair;
  while (rem >= NCH - ci) { rem -= NCH - ci; ci++; }
  int cj = ci + rem;   // cj >= ci (upper triangle)
  __shared__ float cx0[64], cy0[64], cx1[64], cy1[64], car[64];
  int t = threadIdx.x;
  size_t base = (size_t)b * NMSM;
  int j = cj * 64 + t;
  if (j < NMSM) {
    cx0[t] = sx0[base + j]; cy0[t] = sy0[base + j];
    cx1[t] = sx1[base + j]; cy1[t] = sy1[base + j];
    car[t] = sar[base + j];
  }
  __syncthreads();
  int i = ci * 64 + t;
  if (i >= NMSM) return;
  float x0 = sx0[base + i], y0 = sy0[base + i];
  float x1 = sx1[base + i], y1 = sy1[base + i], a = sar[base + i];
  unsigned long long bits = 0ull;
#pragma unroll 8
  for (int jj = 0; jj < 64; jj++) {
    int jg = cj * 64 + jj;
    float xl = fmaxf(x0, cx0[jj]);
    float yt = fmaxf(y0, cy0[jj]);
    float xr = fminf(x1, cx1[jj]);
    float yb = fminf(y1, cy1[jj]);
    float inter = fmaxf(xr - xl, 0.0f) * fmaxf(yb - yt, 0.0f);
    float iou = inter / (a + car[jj] - inter);
    if (jg > i && jg < NMSM && iou > NMS_THR) bits |= 1ull << jj;
  }
  mask[(base + i) * NCH + cj] = bits;
}

// ---------------- stage 4b: pipelined serial reduce + EARLY EXIT -----------
// ONE 64-lane wave per image. Per tick bi: issue DMA for block bi+2 (uniform
// LDS base), vmcnt(11) for block bi+1, consume block bi. EARLY EXIT: output
// needs only the FIRST 200 kept candidates; after committing block bi, if
// cumulative keeps >= 200, every later element's rank is >= 200 (prefix sums
// already >= 200) so their skeep words can be zeroed — break out. Typical
// data keeps most candidates -> exit after ~4 of 22 blocks. Worst case
// degenerates to the full 22.
__global__ __launch_bounds__(64) void nms_serial_kernel(
    const unsigned long long* __restrict__ mask, const int* __restrict__ sord,
    const int* __restrict__ nvalidArr,
    const float* __restrict__ cboxes, const float* __restrict__ cscores,
    float* __restrict__ out, int B) {
  __shared__ __align__(16) unsigned long long rowbuf[NBUF][BWORDS];
  __shared__ unsigned long long skeep[NCH];
  __shared__ int spfx[NCH];
  int b = blockIdx.x;
  int lane = threadIdx.x;
  int nvalid = nvalidArr[b];
  const unsigned long long* M = mask + (size_t)b * NMSM * NCH;

  // alive bit i=1 for sorted positions < nvalid
  unsigned long long remove = 0ull;
  if (lane < NCH) {
    int base = lane * 64;
    if (base + 64 <= nvalid) remove = ~0ull;
    else if (base < nvalid) remove = (~0ull) >> (64 - (nvalid - base));
  }
  bool act = (lane < NCH);
  int li = act ? lane : 0;

  auto stage = [&](int t) {
    const char* srcb = (const char*)(M + (size_t)t * BWORDS) + lane * 16;
    char* dstb = (char*)(rowbuf[t & (NBUF - 1)]);   // WAVE-UNIFORM dst
#pragma unroll
    for (int r = 0; r < NRND; r++) {
      __builtin_amdgcn_global_load_lds(
          (const __attribute__((address_space(1))) void*)(srcb + r * 1024),
          (__attribute__((address_space(3))) void*)(dstb + r * 1024),
          16, 0, 0);
    }
  };

  // prologue: blocks 0 and 1 in flight (22 outstanding)
  stage(0);
  stage(1);

  int kept = 0;
  int processed = 0;
  for (int bi = 0; bi < NCH; bi++) {
    if (bi + 2 < NCH) {
      stage(bi + 2);                                  // newest 11 in flight
      asm volatile("s_waitcnt vmcnt(11)" ::: "memory"); // block bi+1 landed
    } else {
      asm volatile("s_waitcnt vmcnt(0)" ::: "memory");  // tail: drain all
    }
    unsigned long long* rb = rowbuf[bi & (NBUF - 1)];
    // cur = alive word bi, replicated in ALL lanes (VALU chain). Diag words
    // have bits<=d clear, so decided bits are stable.
    unsigned long long cur = __shfl(remove, bi);
    unsigned long long wmask = (act && lane >= bi) ? ~0ull : 0ull;
#pragma unroll 8
    for (int d = 0; d < 64; d++) {
      unsigned long long rowd  = rb[(size_t)d * NCH + li];  // per-lane word
      unsigned long long diagd = rb[(size_t)d * NCH + bi];  // broadcast
      bool kd = (cur >> d) & 1ull;                          // uniform value
      cur    &= ~(kd ? diagd : 0ull);
      remove &= ~(kd ? (rowd & wmask) : 0ull);
    }
    remove = (lane == bi) ? cur : remove;
    kept += (int)__popcll(cur);       // cur uniform across lanes
    processed = bi + 1;
    if (kept >= TOPK) break;          // later ranks provably >= 200
  }

  // unprocessed blocks: rank >= kept >= 200 -> zero their keep words
  if (act) skeep[lane] = (lane < processed) ? remove : 0ull;
  __syncthreads();   // also drains abandoned in-flight DMA (vmcnt(0))
  if (lane == 0) {
    int s = 0;
    for (int w = 0; w < NCH; w++) { spfx[w] = s; s += __popcll(skeep[w]); }
  }
  __syncthreads();

  float* ob = out + (size_t)b * TOPK * 4;
  float* os = out + (size_t)B * TOPK * 4 + (size_t)b * TOPK;
  float* ol = out + (size_t)B * TOPK * 5 + (size_t)b * TOPK;
  for (int r = lane; r < TOPK; r += 64) {
    ob[r * 4 + 0] = 0.0f; ob[r * 4 + 1] = 0.0f;
    ob[r * 4 + 2] = 0.0f; ob[r * 4 + 3] = 0.0f;
    os[r] = 0.0f; ol[r] = 0.0f;
  }
  __syncthreads();
  size_t base = (size_t)b * NMSM;
  for (int i = lane; i < NMSM; i += 64) {
    int w = i >> 6;
    unsigned long long kw = skeep[w];
    if ((kw >> (i & 63)) & 1ull) {
      int r = spfx[w] + __popcll(kw & ((1ull << (i & 63)) - 1ull));
      if (r < TOPK) {
        int m = sord[base + i];
        const float* cb = cboxes + (base + m) * 4;
        ob[r * 4 + 0] = cb[0]; ob[r * 4 + 1] = cb[1];
        ob[r * 4 + 2] = cb[2]; ob[r * 4 + 3] = cb[3];
        os[r] = cscores[base + m];
        ol[r] = (float)(m / TOPK + 1);
      }
    }
  }
}

extern "C" void kernel_launch(void* const* d_in, const int* in_sizes, int n_in,
                              void* d_out, int out_size, void* d_ws, size_t ws_size,
                              hipStream_t stream) {
  const float* logits = (const float*)d_in[0];
  const float* deltas = (const float*)d_in[1];
  const float* dbox   = (const float*)d_in[2];
  int A = in_sizes[2] / 4;
  int B = in_sizes[0] / (A * NCLS);
  int NROWS = B * NFG;
  float* out = (float*)d_out;

  // workspace layout
  float* scores_ws = (float*)d_ws;                                  // B*7*A floats
  float* tval = scores_ws + (size_t)B * NFG * A;                    // B*7*200
  int*   tidx = (int*)(tval + (size_t)B * NFG * TOPK);              // B*7*200
  float* cboxes = (float*)(tidx + (size_t)B * NFG * TOPK);          // B*1400*4
  float* cscores = cboxes + (size_t)B * NMSM * 4;                   // B*1400
  unsigned* ghist = (unsigned*)(cscores + (size_t)B * NMSM);        // 224*2048 u32

  // NMS scratch aliased onto the scores buffer (dead after select_kernel):
  //   mask: B*1400*22 u64 = 7.885 MB at offset 0 (last image's last block
  //   stages 8 padded rows = 1.4 KB past its region — inside the 8 MB window)
  //   sorted arrays at +8 MB (2,097,152 floats)
  unsigned long long* mask = (unsigned long long*)scores_ws;
  float* sbase = scores_ws + 2097152;
  size_t n1 = (size_t)B * NMSM;
  float* sx0 = sbase;            float* sy0 = sbase + n1;
  float* sx1 = sbase + 2 * n1;   float* sy1 = sbase + 3 * n1;
  float* sar = sbase + 4 * n1;
  int*   sord = (int*)(sbase + 5 * n1);
  int*   nvalid = (int*)(sbase + 6 * n1);

  int n16 = NROWS * BINS / 4;   // u32 count / 4 per uint4
  zero_hist_kernel<<<(n16 + 255) / 256, 256, 0, stream>>>((uint4*)ghist, n16);
  score_hist_kernel<<<dim3(HSLICE, B), 1024, 0, stream>>>(logits, scores_ws,
                                                          ghist, A);
  select_kernel<<<NROWS, 1024, 0, stream>>>(scores_ws, ghist, A, tval, tidx);
  nms_sort_kernel<<<B, 1024, 0, stream>>>(deltas, dbox, tval, tidx, cboxes,
                                          cscores, sx0, sy0, sx1, sy1, sar,
                                          sord, nvalid, A);
  nms_mask_kernel<<<dim3(NPAIRS, B), 64, 0, stream>>>(sx0, sy0, sx1, sy1, sar, mask);
  nms_serial_kernel<<<B, 64, 0, stream>>>(mask, sord, nvalid, cboxes, cscores, out, B);
}

// Round 4
// 105.647 us; speedup vs baseline: 1.0438x; 1.0438x over previous
//
#include <hip/hip_runtime.h>
#include <hip/hip_bf16.h>
#include <math.h>

// SSD post-processing for MI355X.
// (1) fused softmax + transpose + per-(b,c) histogram;
// (2) per-(b,c) top-200: single-wave coarse threshold + fine 8-bit refine
//     during collect + rank-by-counting scatter (no big bitonic);
// (3) NMS: fused gather/decode + merge-rank sort -> parallel IoU bitmask ->
//     single-wave pipelined serial reduce with EARLY EXIT at 200 keeps.
//
// R15: select_kernel rewritten. Old: 16-barrier suffix scan + collect +
// bitonic over P up to 4096 (45-78 barrier phases at 1 block/CU = pure wall
// time). New: wave-0 shfl suffix scan (0 barriers), fine 256-bin refine of
// the boundary bucket (survivor set ~200-230), compact, rank-by-counting
// (1 barrier) with direct scatter. Bitonic only as >2048-survivor fallback.
// NOTE (R14 post-mortem): the ~40us fillBufferAligned in rocprof is the
// harness's 268MB per-iteration workspace poison — fixed cost, not ours.

#define NCLS 8
#define NFG 7
#define TOPK 200
#define NMSM (NFG * TOPK)   // 1400
#define NCH 22              // ceil(1400/64) 64-wide chunks
#define NPAIRS (NCH * (NCH + 1) / 2)  // 253 upper-triangle chunk pairs
#define BROWS 64
#define BWORDS (BROWS * NCH)          // 1408 u64 per 64-row mask block
#define NRND 11                       // 1 KB global_load_lds rounds per block
#define NBUF 4                        // LDS ring slots (lead=2, reuse dist 4)
#define HSLICE 16                     // image slices for fused score+hist
#define LOW_SCORE 0.01f
#define NMS_THR 0.45f
#define BINS 2048                     // bits>>19 of score<1.0 is <= 2031
#define CAP 4096

// ---------------- stage 0: zero the global histogram ----------------
__global__ __launch_bounds__(256) void zero_hist_kernel(uint4* __restrict__ p,
                                                        int n16) {
  int i = blockIdx.x * 256 + threadIdx.x;
  if (i < n16) p[i] = make_uint4(0u, 0u, 0u, 0u);
}

// ---------------- stage 1: fused softmax + transpose + histogram ----------
// Grid (HSLICE, B), 1024 threads. Each block: one image slice of A/HSLICE
// anchors. Softmax values go to scores[] (transposed [b][c][a]) AND to a
// 7-row LDS histogram (57 KB -> 2 blocks/CU), flushed with global atomics.
__global__ __launch_bounds__(1024) void score_hist_kernel(
    const float* __restrict__ logits, float* __restrict__ scores,
    unsigned* __restrict__ ghist, int A) {
  __shared__ unsigned hist[NFG * BINS];   // 7*2048*4 = 57344 B
  int tid = threadIdx.x;
  int b = blockIdx.y;
  int slice = blockIdx.x;
  int sl = A / HSLICE;                    // 3066
  for (int i = tid; i < NFG * BINS; i += 1024) hist[i] = 0;
  __syncthreads();

  int a0 = slice * sl;
  for (int k = tid; k < sl; k += 1024) {
    int a = a0 + k;
    const float4* p4 = (const float4*)(logits + ((size_t)b * A + a) * NCLS);
    float4 v0 = p4[0], v1 = p4[1];
    float x[NCLS] = {v0.x, v0.y, v0.z, v0.w, v1.x, v1.y, v1.z, v1.w};
    float mx = x[0];
#pragma unroll
    for (int c = 1; c < NCLS; c++) mx = fmaxf(mx, x[c]);
    float e[NCLS];
    float s = 0.0f;
#pragma unroll
    for (int c = 0; c < NCLS; c++) { e[c] = expf(x[c] - mx); s += e[c]; }
    float inv = 1.0f / s;
#pragma unroll
    for (int c = 1; c < NCLS; c++) {
      float v = e[c] * inv;
      scores[((size_t)b * NFG + (c - 1)) * A + a] = v;
      atomicAdd(&hist[(c - 1) * BINS + (__float_as_uint(v) >> 19)], 1u);
    }
  }
  __syncthreads();

  unsigned* g = ghist + (size_t)b * NFG * BINS;
  for (int i = tid; i < NFG * BINS; i += 1024) {
    unsigned v = hist[i];
    if (v) atomicAdd(&g[i], v);
  }
}

// ---------------- bitonic sort (descending) on shared ulong ----------------
// (kept only as the >2048-survivor fallback path of select_kernel)
__device__ inline void bitonic_desc(unsigned long long* buf, int P, int tid, int nthr) {
  for (int k = 2; k <= P; k <<= 1) {
    for (int j = k >> 1; j > 0; j >>= 1) {
      __syncthreads();
      for (int i = tid; i < P; i += nthr) {
        int l = i ^ j;
        if (l > i) {
          unsigned long long va = buf[i], vb = buf[l];
          bool descRegion = ((i & k) == 0);
          if (descRegion ? (va < vb) : (va > vb)) { buf[i] = vb; buf[l] = va; }
        }
      }
    }
  }
  __syncthreads();
}

// ---------------- stage 2: select threshold + collect + rank-scatter -------
// Per (b,c) row. Wave 0: shfl-based suffix scan over the 2048-bin coarse
// hist -> boundary bucket t + count strictly above it. Collect pass appends
// all values with bucket >= t; boundary-bucket values also feed a 256-bin
// fine histogram of the next 8 mantissa bits. Wave 0 refines to a 21-bit
// threshold (survivors ~200-230). Compact + rank-by-counting scatter.
__global__ __launch_bounds__(1024) void select_kernel(
    const float* __restrict__ scores, const unsigned* __restrict__ ghist, int A,
    float* __restrict__ tval, int* __restrict__ tidx) {
  __shared__ unsigned long long buf[CAP];   // 32 KB: all bucket>=t candidates
  __shared__ unsigned long long fin[CAP];   // 32 KB: compacted survivors
  __shared__ unsigned fineh[256];
  __shared__ int s_t, s_above, s_thr, s_cnt, s_cnt2;
  int tid = threadIdx.x;
  int row = blockIdx.x;  // b*7 + c
  const unsigned* h = ghist + (size_t)row * BINS;
  if (tid == 0) { s_cnt = 0; s_cnt2 = 0; }
  if (tid < 256) fineh[tid] = 0u;

  // ---- coarse threshold: wave 0 only, shfl suffix scan, no barriers ----
  if (tid < 64) {
    int lane = tid;
    const uint4* h4 = (const uint4*)h;
    int s = 0;
#pragma unroll
    for (int k = 0; k < 8; k++) {           // 32 bins per lane
      uint4 v = h4[lane * 8 + k];
      s += (int)(v.x + v.y + v.z + v.w);
    }
    int sfx = s;                            // suffix sum over lanes >= lane
#pragma unroll
    for (int off = 1; off < 64; off <<= 1) {
      int o = __shfl(sfx, lane + off);      // wraps when OOB; masked below
      sfx += (lane + off < 64) ? o : 0;
    }
    int nxt = __shfl(sfx, lane + 1);
    nxt = (lane < 63) ? nxt : 0;
    bool mine = (sfx >= TOPK) && (nxt < TOPK);  // exactly one lane
    if (mine) {
      int cum = nxt;
      int t = lane * 32 + 31;
      for (; t >= lane * 32; t--) { cum += (int)h[t]; if (cum >= TOPK) break; }
      s_t = t;
      s_above = cum - (int)h[t];            // count in buckets strictly > t
    }
  }
  __syncthreads();

  // ---- collect pass: bucket >= t -> buf; bucket == t -> fine histogram ----
  unsigned tbin = (unsigned)s_t;
  const float4* p4 = (const float4*)(scores + (size_t)row * A);
  int n4 = A / 4;
  for (int k = tid; k < n4; k += 1024) {
    float4 v = p4[k];
    float c4[4] = {v.x, v.y, v.z, v.w};
#pragma unroll
    for (int j = 0; j < 4; j++) {
      unsigned key = __float_as_uint(c4[j]);
      unsigned bk = key >> 19;
      if (bk >= tbin) {
        int pos = atomicAdd(&s_cnt, 1);
        if (pos < CAP)
          buf[pos] = ((unsigned long long)key << 32) | (unsigned)(~(4 * k + j));
        if (bk == tbin) atomicAdd(&fineh[(key >> 11) & 255u], 1u);
      }
    }
  }
  __syncthreads();

  // ---- fine threshold: wave 0 only ----
  if (tid < 64) {
    int lane = tid;
    int f0 = (int)fineh[lane * 4 + 0];
    int f1 = (int)fineh[lane * 4 + 1];
    int f2 = (int)fineh[lane * 4 + 2];
    int f3 = (int)fineh[lane * 4 + 3];
    int sfx = f0 + f1 + f2 + f3;
#pragma unroll
    for (int off = 1; off < 64; off <<= 1) {
      int o = __shfl(sfx, lane + off);
      sfx += (lane + off < 64) ? o : 0;
    }
    int nxt = __shfl(sfx, lane + 1);
    nxt = (lane < 63) ? nxt : 0;
    int need = TOPK - s_above;              // >= 1 by construction of t
    int s3 = nxt + f3, s2 = s3 + f2, s1 = s2 + f1, s0 = s1 + f0;
    int t2 = -1;
    if (s3 >= need && nxt < need) t2 = lane * 4 + 3;
    else if (s2 >= need && s3 < need) t2 = lane * 4 + 2;
    else if (s1 >= need && s2 < need) t2 = lane * 4 + 1;
    else if (s0 >= need && s1 < need) t2 = lane * 4 + 0;
    if (t2 >= 0)
      s_thr = (int)(((unsigned)s_t << 19) | ((unsigned)t2 << 11));
  }
  __syncthreads();

  // ---- compact survivors (key >= 21-bit threshold) ----
  unsigned thr = (unsigned)s_thr;
  int cnt = s_cnt; if (cnt > CAP) cnt = CAP;
  for (int i = tid; i < cnt; i += 1024) {
    unsigned long long v = buf[i];
    if ((unsigned)(v >> 32) >= thr) {
      int p = atomicAdd(&s_cnt2, 1);
      fin[p] = v;                           // subset of buf -> fits CAP
    }
  }
  __syncthreads();
  int cnt2 = s_cnt2;
  size_t obase = (size_t)row * TOPK;

  if (cnt2 <= 2048) {
    // rank-by-counting: composite u64 keys are unique -> ranks unique
    for (int i = tid; i < cnt2; i += 1024) {
      unsigned long long my = fin[i];
      int r = 0;
      for (int j = 0; j < cnt2; j++) r += (fin[j] > my);
      if (r < TOPK) {
        tval[obase + r] = __uint_as_float((unsigned)(my >> 32));
        tidx[obase + r] = (int)(~(unsigned)(my & 0xFFFFFFFFull));
      }
    }
    // defensive: pad unreachable ranks (only if truncation dropped survivors)
    for (int r = cnt2 + tid; r < TOPK; r += 1024) {
      tval[obase + r] = 0.0f;
      tidx[obase + r] = 0;
    }
  } else {
    int P = 2048; while (P < cnt2) P <<= 1;  // <= CAP
    for (int i = cnt2 + tid; i < P; i += 1024) fin[i] = 0ull;
    __syncthreads();
    bitonic_desc(fin, P, tid, 1024);
    if (tid < TOPK) {
      unsigned long long v = fin[tid];
      tval[obase + tid] = __uint_as_float((unsigned)(v >> 32));
      tidx[obase + tid] = (int)(~(unsigned)(v & 0xFFFFFFFFull));
    }
  }
}

// ---------------- stage 3: fused gather/decode + per-image merge-rank sort --
// The 1400 candidates are 7 per-class lists, each STRICTLY DESCENDING in the
// composite key (score_bits<<32)|~m. Global sorted position = sum over the 7
// lists of count(key > key_e); own list contributes exactly r. 7 independent
// unrolled binary searches per element (ILP hides LDS latency).
__global__ __launch_bounds__(1024) void nms_sort_kernel(
    const float* __restrict__ deltas, const float* __restrict__ dbox,
    const float* __restrict__ tval, const int* __restrict__ tidx,
    float* __restrict__ cboxes, float* __restrict__ cscores,
    float* __restrict__ sx0, float* __restrict__ sy0,
    float* __restrict__ sx1, float* __restrict__ sy1,
    float* __restrict__ sar, int* __restrict__ sord, int* __restrict__ nvalid,
    int A) {
  __shared__ unsigned long long keys[NMSM];
  __shared__ float bx0[NMSM], by0[NMSM], bx1[NMSM], by1[NMSM];
  __shared__ int s_cnt;
  int tid = threadIdx.x;
  int b = blockIdx.x;
  if (tid == 0) s_cnt = 0;
  __syncthreads();

  int myv = 0;
  for (int m = tid; m < NMSM; m += 1024) {
    int c = m / TOPK;
    int r = m - c * TOPK;
    size_t tk = ((size_t)b * NFG + c) * TOPK + r;
    int a = tidx[tk];
    if (a < 0) a = 0;                       // guard padded entries
    float v = tval[tk];
    // decode
    const float* db = dbox + (size_t)a * 4;
    float w = db[2] - db[0];
    float h = db[3] - db[1];
    float cx = db[0] + 0.5f * w;
    float cy = db[1] + 0.5f * h;
    const float* dd = deltas + ((size_t)b * A + a) * 4;
    float pcx = dd[0] / 10.0f * w + cx;
    float pcy = dd[1] / 10.0f * h + cy;
    float pw = expf(dd[2] / 5.0f) * w;
    float ph = expf(dd[3] / 5.0f) * h;
    float x0 = fminf(fmaxf(pcx - 0.5f * pw, 0.0f), 1.0f);
    float y0 = fminf(fmaxf(pcy - 0.5f * ph, 0.0f), 1.0f);
    float x1 = fminf(fmaxf(pcx + 0.5f * pw, 0.0f), 1.0f);
    float y1 = fminf(fmaxf(pcy + 0.5f * ph, 0.0f), 1.0f);
    size_t gi = (size_t)b * NMSM + m;
    float* cb = cboxes + gi * 4;
    cb[0] = x0; cb[1] = y0; cb[2] = x1; cb[3] = y1;
    cscores[gi] = v;
    bx0[m] = x0; by0[m] = y0; bx1[m] = x1; by1[m] = y1;
    unsigned k32 = (v > LOW_SCORE) ? __float_as_uint(v) : 0u;
    if (k32) myv++;
    keys[m] = ((unsigned long long)k32 << 32) | (unsigned)(~m);
  }
  if (myv) atomicAdd(&s_cnt, myv);
  __syncthreads();

  size_t base = (size_t)b * NMSM;
  for (int m = tid; m < NMSM; m += 1024) {
    unsigned long long k = keys[m];
    int c = m / TOPK;
    int lo[NFG], hi[NFG];
#pragma unroll
    for (int cc = 0; cc < NFG; cc++) { lo[cc] = 0; hi[cc] = TOPK; }
#pragma unroll
    for (int s8 = 0; s8 < 8; s8++) {
#pragma unroll
      for (int cc = 0; cc < NFG; cc++) {
        if (lo[cc] < hi[cc]) {
          int mid = (lo[cc] + hi[cc]) >> 1;
          if (keys[cc * TOPK + mid] > k) lo[cc] = mid + 1; else hi[cc] = mid;
        }
      }
    }
    int p = 0;
#pragma unroll
    for (int cc = 0; cc < NFG; cc++) p += lo[cc];

    float off = 4.0f * (float)(c + 1);
    float x0 = bx0[m] + off, y0 = by0[m] + off;
    float x1 = bx1[m] + off, y1 = by1[m] + off;
    sord[base + p] = m;
    sx0[base + p] = x0; sy0[base + p] = y0;
    sx1[base + p] = x1; sy1[base + p] = y1;
    sar[base + p] = (x1 - x0) * (y1 - y0);
  }
  if (tid == 0) nvalid[b] = s_cnt;
}

// ---------------- stage 4a: suppression bitmask ----------------
// NOTE: only upper-triangle chunk pairs (cj >= ci) are WRITTEN. Words cj < ci
// of a mask row are never initialized (0xAA poison) — consumers MUST NOT
// apply them (wmask in nms_serial_kernel; this broke Round 3).
__global__ __launch_bounds__(64) void nms_mask_kernel(
    const float* __restrict__ sx0, const float* __restrict__ sy0,
    const float* __restrict__ sx1, const float* __restrict__ sy1,
    const float* __restrict__ sar, unsigned long long* __restrict__ mask) {
  int b = blockIdx.y;
  int pair = blockIdx.x;
  int ci = 0, rem = pair;
  while (rem >= NCH - ci) { rem -= NCH - ci; ci++; }
  int cj = ci + rem;   // cj >= ci (upper triangle)
  __shared__ float cx0[64], cy0[64], cx1[64], cy1[64], car[64];
  int t = threadIdx.x;
  size_t base = (size_t)b * NMSM;
  int j = cj * 64 + t;
  if (j < NMSM) {
    cx0[t] = sx0[base + j]; cy0[t] = sy0[base + j];
    cx1[t] = sx1[base + j]; cy1[t] = sy1[base + j];
    car[t] = sar[base + j];
  }
  __syncthreads();
  int i = ci * 64 + t;
  if (i >= NMSM) return;
  float x0 = sx0[base + i], y0 = sy0[base + i];
  float x1 = sx1[base + i], y1 = sy1[base + i], a = sar[base + i];
  unsigned long long bits = 0ull;
#pragma unroll 8
  for (int jj = 0; jj < 64; jj++) {
    int jg = cj * 64 + jj;
    float xl = fmaxf(x0, cx0[jj]);
    float yt = fmaxf(y0, cy0[jj]);
    float xr = fminf(x1, cx1[jj]);
    float yb = fminf(y1, cy1[jj]);
    float inter = fmaxf(xr - xl, 0.0f) * fmaxf(yb - yt, 0.0f);
    float iou = inter / (a + car[jj] - inter);
    if (jg > i && jg < NMSM && iou > NMS_THR) bits |= 1ull << jj;
  }
  mask[(base + i) * NCH + cj] = bits;
}

// ---------------- stage 4b: pipelined serial reduce + EARLY EXIT -----------
// ONE 64-lane wave per image. Per tick bi: issue DMA for block bi+2 (uniform
// LDS base), vmcnt(11) for block bi+1, consume block bi. EARLY EXIT: output
// needs only the FIRST 200 kept candidates; after committing block bi, if
// cumulative keeps >= 200, every later element's rank is >= 200 (prefix sums
// already >= 200) so their skeep words can be zeroed — break out. Typical
// data keeps most candidates -> exit after ~4 of 22 blocks. Worst case
// degenerates to the full 22.
__global__ __launch_bounds__(64) void nms_serial_kernel(
    const unsigned long long* __restrict__ mask, const int* __restrict__ sord,
    const int* __restrict__ nvalidArr,
    const float* __restrict__ cboxes, const float* __restrict__ cscores,
    float* __restrict__ out, int B) {
  __shared__ __align__(16) unsigned long long rowbuf[NBUF][BWORDS];
  __shared__ unsigned long long skeep[NCH];
  __shared__ int spfx[NCH];
  int b = blockIdx.x;
  int lane = threadIdx.x;
  int nvalid = nvalidArr[b];
  const unsigned long long* M = mask + (size_t)b * NMSM * NCH;

  // alive bit i=1 for sorted positions < nvalid
  unsigned long long remove = 0ull;
  if (lane < NCH) {
    int base = lane * 64;
    if (base + 64 <= nvalid) remove = ~0ull;
    else if (base < nvalid) remove = (~0ull) >> (64 - (nvalid - base));
  }
  bool act = (lane < NCH);
  int li = act ? lane : 0;

  auto stage = [&](int t) {
    const char* srcb = (const char*)(M + (size_t)t * BWORDS) + lane * 16;
    char* dstb = (char*)(rowbuf[t & (NBUF - 1)]);   // WAVE-UNIFORM dst
#pragma unroll
    for (int r = 0; r < NRND; r++) {
      __builtin_amdgcn_global_load_lds(
          (const __attribute__((address_space(1))) void*)(srcb + r * 1024),
          (__attribute__((address_space(3))) void*)(dstb + r * 1024),
          16, 0, 0);
    }
  };

  // prologue: blocks 0 and 1 in flight (22 outstanding)
  stage(0);
  stage(1);

  int kept = 0;
  int processed = 0;
  for (int bi = 0; bi < NCH; bi++) {
    if (bi + 2 < NCH) {
      stage(bi + 2);                                  // newest 11 in flight
      asm volatile("s_waitcnt vmcnt(11)" ::: "memory"); // block bi+1 landed
    } else {
      asm volatile("s_waitcnt vmcnt(0)" ::: "memory");  // tail: drain all
    }
    unsigned long long* rb = rowbuf[bi & (NBUF - 1)];
    // cur = alive word bi, replicated in ALL lanes (VALU chain). Diag words
    // have bits<=d clear, so decided bits are stable.
    unsigned long long cur = __shfl(remove, bi);
    unsigned long long wmask = (act && lane >= bi) ? ~0ull : 0ull;
#pragma unroll 8
    for (int d = 0; d < 64; d++) {
      unsigned long long rowd  = rb[(size_t)d * NCH + li];  // per-lane word
      unsigned long long diagd = rb[(size_t)d * NCH + bi];  // broadcast
      bool kd = (cur >> d) & 1ull;                          // uniform value
      cur    &= ~(kd ? diagd : 0ull);
      remove &= ~(kd ? (rowd & wmask) : 0ull);
    }
    remove = (lane == bi) ? cur : remove;
    kept += (int)__popcll(cur);       // cur uniform across lanes
    processed = bi + 1;
    if (kept >= TOPK) break;          // later ranks provably >= 200
  }

  // unprocessed blocks: rank >= kept >= 200 -> zero their keep words
  if (act) skeep[lane] = (lane < processed) ? remove : 0ull;
  __syncthreads();   // also drains abandoned in-flight DMA (vmcnt(0))
  if (lane == 0) {
    int s = 0;
    for (int w = 0; w < NCH; w++) { spfx[w] = s; s += __popcll(skeep[w]); }
  }
  __syncthreads();

  float* ob = out + (size_t)b * TOPK * 4;
  float* os = out + (size_t)B * TOPK * 4 + (size_t)b * TOPK;
  float* ol = out + (size_t)B * TOPK * 5 + (size_t)b * TOPK;
  for (int r = lane; r < TOPK; r += 64) {
    ob[r * 4 + 0] = 0.0f; ob[r * 4 + 1] = 0.0f;
    ob[r * 4 + 2] = 0.0f; ob[r * 4 + 3] = 0.0f;
    os[r] = 0.0f; ol[r] = 0.0f;
  }
  __syncthreads();
  size_t base = (size_t)b * NMSM;
  for (int i = lane; i < NMSM; i += 64) {
    int w = i >> 6;
    unsigned long long kw = skeep[w];
    if ((kw >> (i & 63)) & 1ull) {
      int r = spfx[w] + __popcll(kw & ((1ull << (i & 63)) - 1ull));
      if (r < TOPK) {
        int m = sord[base + i];
        const float* cb = cboxes + (base + m) * 4;
        ob[r * 4 + 0] = cb[0]; ob[r * 4 + 1] = cb[1];
        ob[r * 4 + 2] = cb[2]; ob[r * 4 + 3] = cb[3];
        os[r] = cscores[base + m];
        ol[r] = (float)(m / TOPK + 1);
      }
    }
  }
}

extern "C" void kernel_launch(void* const* d_in, const int* in_sizes, int n_in,
                              void* d_out, int out_size, void* d_ws, size_t ws_size,
                              hipStream_t stream) {
  const float* logits = (const float*)d_in[0];
  const float* deltas = (const float*)d_in[1];
  const float* dbox   = (const float*)d_in[2];
  int A = in_sizes[2] / 4;
  int B = in_sizes[0] / (A * NCLS);
  int NROWS = B * NFG;
  float* out = (float*)d_out;

  // workspace layout
  float* scores_ws = (float*)d_ws;                                  // B*7*A floats
  float* tval = scores_ws + (size_t)B * NFG * A;                    // B*7*200
  int*   tidx = (int*)(tval + (size_t)B * NFG * TOPK);              // B*7*200
  float* cboxes = (float*)(tidx + (size_t)B * NFG * TOPK);          // B*1400*4
  float* cscores = cboxes + (size_t)B * NMSM * 4;                   // B*1400
  unsigned* ghist = (unsigned*)(cscores + (size_t)B * NMSM);        // 224*2048 u32

  // NMS scratch aliased onto the scores buffer (dead after select_kernel):
  //   mask: B*1400*22 u64 = 7.885 MB at offset 0 (last image's last block
  //   stages 8 padded rows = 1.4 KB past its region — inside the 8 MB window)
  //   sorted arrays at +8 MB (2,097,152 floats)
  unsigned long long* mask = (unsigned long long*)scores_ws;
  float* sbase = scores_ws + 2097152;
  size_t n1 = (size_t)B * NMSM;
  float* sx0 = sbase;            float* sy0 = sbase + n1;
  float* sx1 = sbase + 2 * n1;   float* sy1 = sbase + 3 * n1;
  float* sar = sbase + 4 * n1;
  int*   sord = (int*)(sbase + 5 * n1);
  int*   nvalid = (int*)(sbase + 6 * n1);

  int n16 = NROWS * BINS / 4;   // u32 count / 4 per uint4
  zero_hist_kernel<<<(n16 + 255) / 256, 256, 0, stream>>>((uint4*)ghist, n16);
  score_hist_kernel<<<dim3(HSLICE, B), 1024, 0, stream>>>(logits, scores_ws,
                                                          ghist, A);
  select_kernel<<<NROWS, 1024, 0, stream>>>(scores_ws, ghist, A, tval, tidx);
  nms_sort_kernel<<<B, 1024, 0, stream>>>(deltas, dbox, tval, tidx, cboxes,
                                          cscores, sx0, sy0, sx1, sy1, sar,
                                          sord, nvalid, A);
  nms_mask_kernel<<<dim3(NPAIRS, B), 64, 0, stream>>>(sx0, sy0, sx1, sy1, sar, mask);
  nms_serial_kernel<<<B, 64, 0, stream>>>(mask, sord, nvalid, cboxes, cscores, out, B);
}

// Round 5
// 100.917 us; speedup vs baseline: 1.0927x; 1.0469x over previous
//
#include <hip/hip_runtime.h>
#include <hip/hip_bf16.h>
#include <math.h>

// SSD post-processing for MI355X.
// (1) fused softmax + transpose + per-(b,c) histogram, storing 16-bit
//     monotone keys (f32bits>>16) instead of f32 scores (halves traffic);
// (2) per-(b,c) top-200: coarse 13-bit + fine 3-bit threshold (=key16 of the
//     200th value exactly), collect survivors, recompute EXACT f32 scores
//     from logits for ~200-260 survivors, rank-by-counting scatter;
// (3) NMS: fused gather/decode + merge-rank sort -> parallel IoU bitmask ->
//     single-wave pipelined serial reduce with EARLY EXIT at 200 keeps.
//
// R16: key16 restructure. Monotone truncation => thr16 == key16(v200)
// (count(key16>=t)>=200 forces t<=key16(v200)); survivors = top-200 +
// 16-bit ties; exact rescore from logits uses the IDENTICAL op order as
// score_hist (no fast-math) => bit-identical output. Traffic: -22 MB write,
// -22 MB read. NOTE: the ~40us fillBufferAligned in rocprof is the
// harness's 268MB per-iteration workspace poison — fixed cost, not ours.

#define NCLS 8
#define NFG 7
#define TOPK 200
#define NMSM (NFG * TOPK)   // 1400
#define NCH 22              // ceil(1400/64) 64-wide chunks
#define NPAIRS (NCH * (NCH + 1) / 2)  // 253 upper-triangle chunk pairs
#define BROWS 64
#define BWORDS (BROWS * NCH)          // 1408 u64 per 64-row mask block
#define NRND 11                       // 1 KB global_load_lds rounds per block
#define NBUF 4                        // LDS ring slots (lead=2, reuse dist 4)
#define HSLICE 16                     // image slices for fused score+hist
#define LOW_SCORE 0.01f
#define NMS_THR 0.45f
#define BINS 2048                     // bits>>19 of score<1.0 is <= 2031
#define CAP 4096

// ---------------- stage 0: zero the global histogram ----------------
__global__ __launch_bounds__(256) void zero_hist_kernel(uint4* __restrict__ p,
                                                        int n16) {
  int i = blockIdx.x * 256 + threadIdx.x;
  if (i < n16) p[i] = make_uint4(0u, 0u, 0u, 0u);
}

// ---------------- stage 1: fused softmax + transpose + key16 + histogram ---
// Grid (HSLICE, B), 1024 threads. Each block: one image slice of A/HSLICE
// anchors. key16 = f32bits>>16 (monotone for positive floats) goes to
// skeys[] (transposed [b][c][a]) AND feeds a 7-row LDS histogram (57 KB ->
// 2 blocks/CU), flushed with global atomics. bucket = key16>>3 = bits>>19.
__global__ __launch_bounds__(1024) void score_hist_kernel(
    const float* __restrict__ logits, unsigned short* __restrict__ skeys,
    unsigned* __restrict__ ghist, int A) {
  __shared__ unsigned hist[NFG * BINS];   // 7*2048*4 = 57344 B
  int tid = threadIdx.x;
  int b = blockIdx.y;
  int slice = blockIdx.x;
  int sl = A / HSLICE;                    // 3066
  for (int i = tid; i < NFG * BINS; i += 1024) hist[i] = 0;
  __syncthreads();

  int a0 = slice * sl;
  for (int k = tid; k < sl; k += 1024) {
    int a = a0 + k;
    const float4* p4 = (const float4*)(logits + ((size_t)b * A + a) * NCLS);
    float4 v0 = p4[0], v1 = p4[1];
    float x[NCLS] = {v0.x, v0.y, v0.z, v0.w, v1.x, v1.y, v1.z, v1.w};
    float mx = x[0];
#pragma unroll
    for (int c = 1; c < NCLS; c++) mx = fmaxf(mx, x[c]);
    float e[NCLS];
    float s = 0.0f;
#pragma unroll
    for (int c = 0; c < NCLS; c++) { e[c] = expf(x[c] - mx); s += e[c]; }
    float inv = 1.0f / s;
#pragma unroll
    for (int c = 1; c < NCLS; c++) {
      unsigned bits = __float_as_uint(e[c] * inv);
      skeys[((size_t)b * NFG + (c - 1)) * A + a] = (unsigned short)(bits >> 16);
      atomicAdd(&hist[(c - 1) * BINS + (bits >> 19)], 1u);
    }
  }
  __syncthreads();

  unsigned* g = ghist + (size_t)b * NFG * BINS;
  for (int i = tid; i < NFG * BINS; i += 1024) {
    unsigned v = hist[i];
    if (v) atomicAdd(&g[i], v);
  }
}

// ---------------- stage 2: select threshold + collect + exact rescore ------
// Per (b,c) row. Wave 0: shfl suffix scan over the 2048-bin coarse hist ->
// boundary bucket t + count strictly above. Collect pass (u32-packed
// key16<<16|idx; A<65536 so idx fits 16 bits); boundary-bucket values feed
// an 8-bin fine histogram of key16&7 -> thr16 (== key16 of the 200th value).
// Survivors (~200-260) get exact f32 recomputed from logits (same op order
// as score_hist => bit-identical), then rank-by-counting scatter.
__global__ __launch_bounds__(1024) void select_kernel(
    const unsigned short* __restrict__ skeys, const unsigned* __restrict__ ghist,
    const float* __restrict__ logits, int A,
    float* __restrict__ tval, int* __restrict__ tidx) {
  __shared__ unsigned buf[CAP];             // 16 KB: bucket>=t candidates
  __shared__ unsigned long long fin[CAP];   // 32 KB: survivors (exact keys)
  __shared__ unsigned fineh[8];
  __shared__ int s_t, s_above, s_thr, s_cnt, s_cnt2;
  int tid = threadIdx.x;
  int row = blockIdx.x;  // b*7 + cc  (cc = class-1)
  int b = row / NFG;
  int cc = row - b * NFG;
  const unsigned* h = ghist + (size_t)row * BINS;
  if (tid == 0) { s_cnt = 0; s_cnt2 = 0; }
  if (tid < 8) fineh[tid] = 0u;

  // ---- coarse threshold: wave 0 only, shfl suffix scan, no barriers ----
  if (tid < 64) {
    int lane = tid;
    const uint4* h4 = (const uint4*)h;
    int s = 0;
#pragma unroll
    for (int k = 0; k < 8; k++) {           // 32 bins per lane
      uint4 v = h4[lane * 8 + k];
      s += (int)(v.x + v.y + v.z + v.w);
    }
    int sfx = s;                            // suffix sum over lanes >= lane
#pragma unroll
    for (int off = 1; off < 64; off <<= 1) {
      int o = __shfl(sfx, lane + off);      // wraps when OOB; masked below
      sfx += (lane + off < 64) ? o : 0;
    }
    int nxt = __shfl(sfx, lane + 1);
    nxt = (lane < 63) ? nxt : 0;
    bool mine = (sfx >= TOPK) && (nxt < TOPK);  // exactly one lane
    if (mine) {
      int cum = nxt;
      int t = lane * 32 + 31;
      for (; t >= lane * 32; t--) { cum += (int)h[t]; if (cum >= TOPK) break; }
      s_t = t;
      s_above = cum - (int)h[t];            // count in buckets strictly > t
    }
  }
  __syncthreads();

  // ---- collect pass: bucket >= t -> buf; bucket == t -> 8-bin fine hist ----
  unsigned tbin = (unsigned)s_t;
  const uint4* p4 = (const uint4*)(skeys + (size_t)row * A);
  int n8 = A / 8;                           // 6132 (A divisible by 8)
  for (int k = tid; k < n8; k += 1024) {
    uint4 v = p4[k];
    unsigned wds[4] = {v.x, v.y, v.z, v.w};
#pragma unroll
    for (int w = 0; w < 4; w++) {
#pragma unroll
      for (int hf = 0; hf < 2; hf++) {
        unsigned k16 = (wds[w] >> (16 * hf)) & 0xFFFFu;
        if ((k16 >> 3) >= tbin) {
          int pos = atomicAdd(&s_cnt, 1);
          if (pos < CAP) buf[pos] = (k16 << 16) | (unsigned)(8 * k + 2 * w + hf);
          if ((k16 >> 3) == tbin) atomicAdd(&fineh[k16 & 7u], 1u);
        }
      }
    }
  }
  __syncthreads();

  // ---- fine threshold (8 sub-levels): thr16 == key16 of the 200th value ----
  if (tid == 0) {
    int need = TOPK - s_above;              // >= 1 by construction of t
    int sfx = 0, t2 = 0;
    for (int t = 7; t >= 0; t--) {
      sfx += (int)fineh[t];
      if (sfx >= need) { t2 = t; break; }
    }
    s_thr = (int)((tbin << 3) | (unsigned)t2);
  }
  __syncthreads();

  // ---- survivors: exact rescore from logits + append composite key ----
  unsigned thr = (unsigned)s_thr;
  int cnt = s_cnt; if (cnt > CAP) cnt = CAP;
  for (int i = tid; i < cnt; i += 1024) {
    unsigned v = buf[i];
    if ((v >> 16) >= thr) {
      int idx = (int)(v & 0xFFFFu);
      // recompute softmax value with IDENTICAL op order as score_hist
      const float4* lp = (const float4*)(logits + ((size_t)b * A + idx) * NCLS);
      float4 v0 = lp[0], v1 = lp[1];
      float x[NCLS] = {v0.x, v0.y, v0.z, v0.w, v1.x, v1.y, v1.z, v1.w};
      float mx = x[0];
#pragma unroll
      for (int c = 1; c < NCLS; c++) mx = fmaxf(mx, x[c]);
      float e[NCLS];
      float s = 0.0f;
#pragma unroll
      for (int c = 0; c < NCLS; c++) { e[c] = expf(x[c] - mx); s += e[c]; }
      float inv = 1.0f / s;
      unsigned bits = __float_as_uint(e[cc + 1] * inv);
      int p = atomicAdd(&s_cnt2, 1);
      if (p < CAP)
        fin[p] = ((unsigned long long)bits << 32) | (unsigned)(~idx);
    }
  }
  __syncthreads();
  int cnt2 = s_cnt2; if (cnt2 > CAP) cnt2 = CAP;
  size_t obase = (size_t)row * TOPK;

  // rank-by-counting: composite u64 keys are unique -> ranks unique
  for (int i = tid; i < cnt2; i += 1024) {
    unsigned long long my = fin[i];
    int r = 0;
    for (int j = 0; j < cnt2; j++) r += (fin[j] > my);
    if (r < TOPK) {
      tval[obase + r] = __uint_as_float((unsigned)(my >> 32));
      tidx[obase + r] = (int)(~(unsigned)(my & 0xFFFFFFFFull));
    }
  }
  // defensive pad (unreachable unless pathological tie overflow)
  for (int r = cnt2 + tid; r < TOPK; r += 1024) {
    tval[obase + r] = 0.0f;
    tidx[obase + r] = 0;
  }
}

// ---------------- stage 3: fused gather/decode + per-image merge-rank sort --
// The 1400 candidates are 7 per-class lists, each STRICTLY DESCENDING in the
// composite key (score_bits<<32)|~m. Global sorted position = sum over the 7
// lists of count(key > key_e); own list contributes exactly r. 7 independent
// unrolled binary searches per element (ILP hides LDS latency).
__global__ __launch_bounds__(1024) void nms_sort_kernel(
    const float* __restrict__ deltas, const float* __restrict__ dbox,
    const float* __restrict__ tval, const int* __restrict__ tidx,
    float* __restrict__ cboxes, float* __restrict__ cscores,
    float* __restrict__ sx0, float* __restrict__ sy0,
    float* __restrict__ sx1, float* __restrict__ sy1,
    float* __restrict__ sar, int* __restrict__ sord, int* __restrict__ nvalid,
    int A) {
  __shared__ unsigned long long keys[NMSM];
  __shared__ float bx0[NMSM], by0[NMSM], bx1[NMSM], by1[NMSM];
  __shared__ int s_cnt;
  int tid = threadIdx.x;
  int b = blockIdx.x;
  if (tid == 0) s_cnt = 0;
  __syncthreads();

  int myv = 0;
  for (int m = tid; m < NMSM; m += 1024) {
    int c = m / TOPK;
    int r = m - c * TOPK;
    size_t tk = ((size_t)b * NFG + c) * TOPK + r;
    int a = tidx[tk];
    if (a < 0) a = 0;                       // guard padded entries
    float v = tval[tk];
    // decode
    const float* db = dbox + (size_t)a * 4;
    float w = db[2] - db[0];
    float h = db[3] - db[1];
    float cx = db[0] + 0.5f * w;
    float cy = db[1] + 0.5f * h;
    const float* dd = deltas + ((size_t)b * A + a) * 4;
    float pcx = dd[0] / 10.0f * w + cx;
    float pcy = dd[1] / 10.0f * h + cy;
    float pw = expf(dd[2] / 5.0f) * w;
    float ph = expf(dd[3] / 5.0f) * h;
    float x0 = fminf(fmaxf(pcx - 0.5f * pw, 0.0f), 1.0f);
    float y0 = fminf(fmaxf(pcy - 0.5f * ph, 0.0f), 1.0f);
    float x1 = fminf(fmaxf(pcx + 0.5f * pw, 0.0f), 1.0f);
    float y1 = fminf(fmaxf(pcy + 0.5f * ph, 0.0f), 1.0f);
    size_t gi = (size_t)b * NMSM + m;
    float* cb = cboxes + gi * 4;
    cb[0] = x0; cb[1] = y0; cb[2] = x1; cb[3] = y1;
    cscores[gi] = v;
    bx0[m] = x0; by0[m] = y0; bx1[m] = x1; by1[m] = y1;
    unsigned k32 = (v > LOW_SCORE) ? __float_as_uint(v) : 0u;
    if (k32) myv++;
    keys[m] = ((unsigned long long)k32 << 32) | (unsigned)(~m);
  }
  if (myv) atomicAdd(&s_cnt, myv);
  __syncthreads();

  size_t base = (size_t)b * NMSM;
  for (int m = tid; m < NMSM; m += 1024) {
    unsigned long long k = keys[m];
    int c = m / TOPK;
    int lo[NFG], hi[NFG];
#pragma unroll
    for (int cc = 0; cc < NFG; cc++) { lo[cc] = 0; hi[cc] = TOPK; }
#pragma unroll
    for (int s8 = 0; s8 < 8; s8++) {
#pragma unroll
      for (int cc = 0; cc < NFG; cc++) {
        if (lo[cc] < hi[cc]) {
          int mid = (lo[cc] + hi[cc]) >> 1;
          if (keys[cc * TOPK + mid] > k) lo[cc] = mid + 1; else hi[cc] = mid;
        }
      }
    }
    int p = 0;
#pragma unroll
    for (int cc = 0; cc < NFG; cc++) p += lo[cc];

    float off = 4.0f * (float)(c + 1);
    float x0 = bx0[m] + off, y0 = by0[m] + off;
    float x1 = bx1[m] + off, y1 = by1[m] + off;
    sord[base + p] = m;
    sx0[base + p] = x0; sy0[base + p] = y0;
    sx1[base + p] = x1; sy1[base + p] = y1;
    sar[base + p] = (x1 - x0) * (y1 - y0);
  }
  if (tid == 0) nvalid[b] = s_cnt;
}

// ---------------- stage 4a: suppression bitmask ----------------
// NOTE: only upper-triangle chunk pairs (cj >= ci) are WRITTEN. Words cj < ci
// of a mask row are never initialized (0xAA poison) — consumers MUST NOT
// apply them (wmask in nms_serial_kernel; this broke Round 3).
__global__ __launch_bounds__(64) void nms_mask_kernel(
    const float* __restrict__ sx0, const float* __restrict__ sy0,
    const float* __restrict__ sx1, const float* __restrict__ sy1,
    const float* __restrict__ sar, unsigned long long* __restrict__ mask) {
  int b = blockIdx.y;
  int pair = blockIdx.x;
  int ci = 0, rem = pair;
  while (rem >= NCH - ci) { rem -= NCH - ci; ci++; }
  int cj = ci + rem;   // cj >= ci (upper triangle)
  __shared__ float cx0[64], cy0[64], cx1[64], cy1[64], car[64];
  int t = threadIdx.x;
  size_t base = (size_t)b * NMSM;
  int j = cj * 64 + t;
  if (j < NMSM) {
    cx0[t] = sx0[base + j]; cy0[t] = sy0[base + j];
    cx1[t] = sx1[base + j]; cy1[t] = sy1[base + j];
    car[t] = sar[base + j];
  }
  __syncthreads();
  int i = ci * 64 + t;
  if (i >= NMSM) return;
  float x0 = sx0[base + i], y0 = sy0[base + i];
  float x1 = sx1[base + i], y1 = sy1[base + i], a = sar[base + i];
  unsigned long long bits = 0ull;
#pragma unroll 8
  for (int jj = 0; jj < 64; jj++) {
    int jg = cj * 64 + jj;
    float xl = fmaxf(x0, cx0[jj]);
    float yt = fmaxf(y0, cy0[jj]);
    float xr = fminf(x1, cx1[jj]);
    float yb = fminf(y1, cy1[jj]);
    float inter = fmaxf(xr - xl, 0.0f) * fmaxf(yb - yt, 0.0f);
    float iou = inter / (a + car[jj] - inter);
    if (jg > i && jg < NMSM && iou > NMS_THR) bits |= 1ull << jj;
  }
  mask[(base + i) * NCH + cj] = bits;
}

// ---------------- stage 4b: pipelined serial reduce + EARLY EXIT -----------
// ONE 64-lane wave per image. Per tick bi: issue DMA for block bi+2 (uniform
// LDS base), vmcnt(11) for block bi+1, consume block bi. EARLY EXIT: output
// needs only the FIRST 200 kept candidates; after committing block bi, if
// cumulative keeps >= 200, every later element's rank is >= 200 (prefix sums
// already >= 200) so their skeep words can be zeroed — break out. Typical
// data keeps most candidates -> exit after ~4 of 22 blocks. Worst case
// degenerates to the full 22.
__global__ __launch_bounds__(64) void nms_serial_kernel(
    const unsigned long long* __restrict__ mask, const int* __restrict__ sord,
    const int* __restrict__ nvalidArr,
    const float* __restrict__ cboxes, const float* __restrict__ cscores,
    float* __restrict__ out, int B) {
  __shared__ __align__(16) unsigned long long rowbuf[NBUF][BWORDS];
  __shared__ unsigned long long skeep[NCH];
  __shared__ int spfx[NCH];
  int b = blockIdx.x;
  int lane = threadIdx.x;
  int nvalid = nvalidArr[b];
  const unsigned long long* M = mask + (size_t)b * NMSM * NCH;

  // alive bit i=1 for sorted positions < nvalid
  unsigned long long remove = 0ull;
  if (lane < NCH) {
    int base = lane * 64;
    if (base + 64 <= nvalid) remove = ~0ull;
    else if (base < nvalid) remove = (~0ull) >> (64 - (nvalid - base));
  }
  bool act = (lane < NCH);
  int li = act ? lane : 0;

  auto stage = [&](int t) {
    const char* srcb = (const char*)(M + (size_t)t * BWORDS) + lane * 16;
    char* dstb = (char*)(rowbuf[t & (NBUF - 1)]);   // WAVE-UNIFORM dst
#pragma unroll
    for (int r = 0; r < NRND; r++) {
      __builtin_amdgcn_global_load_lds(
          (const __attribute__((address_space(1))) void*)(srcb + r * 1024),
          (__attribute__((address_space(3))) void*)(dstb + r * 1024),
          16, 0, 0);
    }
  };

  // prologue: blocks 0 and 1 in flight (22 outstanding)
  stage(0);
  stage(1);

  int kept = 0;
  int processed = 0;
  for (int bi = 0; bi < NCH; bi++) {
    if (bi + 2 < NCH) {
      stage(bi + 2);                                  // newest 11 in flight
      asm volatile("s_waitcnt vmcnt(11)" ::: "memory"); // block bi+1 landed
    } else {
      asm volatile("s_waitcnt vmcnt(0)" ::: "memory");  // tail: drain all
    }
    unsigned long long* rb = rowbuf[bi & (NBUF - 1)];
    // cur = alive word bi, replicated in ALL lanes (VALU chain). Diag words
    // have bits<=d clear, so decided bits are stable.
    unsigned long long cur = __shfl(remove, bi);
    unsigned long long wmask = (act && lane >= bi) ? ~0ull : 0ull;
#pragma unroll 8
    for (int d = 0; d < 64; d++) {
      unsigned long long rowd  = rb[(size_t)d * NCH + li];  // per-lane word
      unsigned long long diagd = rb[(size_t)d * NCH + bi];  // broadcast
      bool kd = (cur >> d) & 1ull;                          // uniform value
      cur    &= ~(kd ? diagd : 0ull);
      remove &= ~(kd ? (rowd & wmask) : 0ull);
    }
    remove = (lane == bi) ? cur : remove;
    kept += (int)__popcll(cur);       // cur uniform across lanes
    processed = bi + 1;
    if (kept >= TOPK) break;          // later ranks provably >= 200
  }

  // unprocessed blocks: rank >= kept >= 200 -> zero their keep words
  if (act) skeep[lane] = (lane < processed) ? remove : 0ull;
  __syncthreads();   // also drains abandoned in-flight DMA (vmcnt(0))
  if (lane == 0) {
    int s = 0;
    for (int w = 0; w < NCH; w++) { spfx[w] = s; s += __popcll(skeep[w]); }
  }
  __syncthreads();

  float* ob = out + (size_t)b * TOPK * 4;
  float* os = out + (size_t)B * TOPK * 4 + (size_t)b * TOPK;
  float* ol = out + (size_t)B * TOPK * 5 + (size_t)b * TOPK;
  for (int r = lane; r < TOPK; r += 64) {
    ob[r * 4 + 0] = 0.0f; ob[r * 4 + 1] = 0.0f;
    ob[r * 4 + 2] = 0.0f; ob[r * 4 + 3] = 0.0f;
    os[r] = 0.0f; ol[r] = 0.0f;
  }
  __syncthreads();
  size_t base = (size_t)b * NMSM;
  for (int i = lane; i < NMSM; i += 64) {
    int w = i >> 6;
    unsigned long long kw = skeep[w];
    if ((kw >> (i & 63)) & 1ull) {
      int r = spfx[w] + __popcll(kw & ((1ull << (i & 63)) - 1ull));
      if (r < TOPK) {
        int m = sord[base + i];
        const float* cb = cboxes + (base + m) * 4;
        ob[r * 4 + 0] = cb[0]; ob[r * 4 + 1] = cb[1];
        ob[r * 4 + 2] = cb[2]; ob[r * 4 + 3] = cb[3];
        os[r] = cscores[base + m];
        ol[r] = (float)(m / TOPK + 1);
      }
    }
  }
}

extern "C" void kernel_launch(void* const* d_in, const int* in_sizes, int n_in,
                              void* d_out, int out_size, void* d_ws, size_t ws_size,
                              hipStream_t stream) {
  const float* logits = (const float*)d_in[0];
  const float* deltas = (const float*)d_in[1];
  const float* dbox   = (const float*)d_in[2];
  int A = in_sizes[2] / 4;
  int B = in_sizes[0] / (A * NCLS);
  int NROWS = B * NFG;
  float* out = (float*)d_out;

  // workspace layout (key16 array is HALF the old f32 scores array)
  unsigned short* skeys = (unsigned short*)d_ws;                    // B*7*A u16
  float* tval = (float*)(skeys + (size_t)B * NFG * A);              // B*7*200
  int*   tidx = (int*)(tval + (size_t)B * NFG * TOPK);              // B*7*200
  float* cboxes = (float*)(tidx + (size_t)B * NFG * TOPK);          // B*1400*4
  float* cscores = cboxes + (size_t)B * NMSM * 4;                   // B*1400
  unsigned* ghist = (unsigned*)(cscores + (size_t)B * NMSM);        // 224*2048 u32

  // NMS scratch aliased onto the skeys buffer (dead after select_kernel):
  //   mask: B*1400*22 u64 = 7.885 MB at offset 0 (last image's last block
  //   stages 8 padded rows = 1.4 KB past its region — inside the 8 MB window)
  //   sorted arrays at byte offset 8 MB (within skeys' 22 MB)
  unsigned long long* mask = (unsigned long long*)d_ws;
  float* sbase = (float*)d_ws + 2097152;
  size_t n1 = (size_t)B * NMSM;
  float* sx0 = sbase;            float* sy0 = sbase + n1;
  float* sx1 = sbase + 2 * n1;   float* sy1 = sbase + 3 * n1;
  float* sar = sbase + 4 * n1;
  int*   sord = (int*)(sbase + 5 * n1);
  int*   nvalid = (int*)(sbase + 6 * n1);

  int n16 = NROWS * BINS / 4;   // u32 count / 4 per uint4
  zero_hist_kernel<<<(n16 + 255) / 256, 256, 0, stream>>>((uint4*)ghist, n16);
  score_hist_kernel<<<dim3(HSLICE, B), 1024, 0, stream>>>(logits, skeys,
                                                          ghist, A);
  select_kernel<<<NROWS, 1024, 0, stream>>>(skeys, ghist, logits, A, tval, tidx);
  nms_sort_kernel<<<B, 1024, 0, stream>>>(deltas, dbox, tval, tidx, cboxes,
                                          cscores, sx0, sy0, sx1, sy1, sar,
                                          sord, nvalid, A);
  nms_mask_kernel<<<dim3(NPAIRS, B), 64, 0, stream>>>(sx0, sy0, sx1, sy1, sar, mask);
  nms_serial_kernel<<<B, 64, 0, stream>>>(mask, sord, nvalid, cboxes, cscores, out, B);
}

// Round 6
// 97.120 us; speedup vs baseline: 1.1354x; 1.0391x over previous
//
#include <hip/hip_runtime.h>
#include <hip/hip_bf16.h>
#include <math.h>

// SSD post-processing for MI355X.
// (1) pure softmax -> 16-bit monotone keys (f32bits>>16), packed u32 stores;
// (2) per-(b,c) top-200: select builds its OWN 2048-bin LDS histogram from
//     the skeys row (row is re-read for collect anyway; 2nd pass is L2-hot),
//     coarse+fine threshold (= key16 of the 200th value exactly), exact
//     rescore from logits for ~200-260 survivors, rank-by-counting scatter;
// (3) NMS: fused gather/decode + merge-rank sort -> parallel IoU bitmask ->
//     single-wave pipelined serial reduce with EARLY EXIT at 200 keeps.
//
// R17: ghist + zero_hist deleted (6 -> 5 dispatches). The global histogram
// was redundant: select re-reads the full row anyway, so it can histogram
// locally. score_kernel loses LDS hist + 7 atomics/anchor + global flush,
// gains 2-anchor/thread packed u32 stores (full-rate on the 22 MB write).
// Considered+rejected: fusing mask into the 32-block serial kernel (on-
// demand 64x1400 IoU/tick on ONE CU ~ 6us/tick >> full-grid mask's 8us
// total). NOTE: the ~40us fillBufferAligned in rocprof is the harness's
// 268MB per-iteration workspace poison — fixed cost, not ours.

#define NCLS 8
#define NFG 7
#define TOPK 200
#define NMSM (NFG * TOPK)   // 1400
#define NCH 22              // ceil(1400/64) 64-wide chunks
#define NPAIRS (NCH * (NCH + 1) / 2)  // 253 upper-triangle chunk pairs
#define BROWS 64
#define BWORDS (BROWS * NCH)          // 1408 u64 per 64-row mask block
#define NRND 11                       // 1 KB global_load_lds rounds per block
#define NBUF 4                        // LDS ring slots (lead=2, reuse dist 4)
#define HSLICE 16                     // image slices for score kernel
#define LOW_SCORE 0.01f
#define NMS_THR 0.45f
#define BINS 2048                     // bits>>19 of score<1.0 is <= 2031
#define CAP 4096

// ---------------- stage 1: softmax -> packed key16 ----------------
// Grid (HSLICE, B), 1024 threads, 2 consecutive anchors per thread.
// key16 = f32bits>>16 (monotone for positive floats), two keys packed into
// one u32 store (full-rate 4 B/lane on the 22 MB write).
__global__ __launch_bounds__(1024) void score_kernel(
    const float* __restrict__ logits, unsigned* __restrict__ skeys32, int A) {
  int tid = threadIdx.x;
  int b = blockIdx.y;
  int slice = blockIdx.x;
  int sl = A / HSLICE;                    // 3066 (even)
  int a0 = slice * sl;
  int npair = sl >> 1;                    // 1533
  for (int k = tid; k < npair; k += 1024) {
    int a = a0 + 2 * k;
    const float4* p4 = (const float4*)(logits + ((size_t)b * A + a) * NCLS);
    float4 v0 = p4[0], v1 = p4[1], v2 = p4[2], v3 = p4[3];
    float x0[NCLS] = {v0.x, v0.y, v0.z, v0.w, v1.x, v1.y, v1.z, v1.w};
    float x1[NCLS] = {v2.x, v2.y, v2.z, v2.w, v3.x, v3.y, v3.z, v3.w};
    float mx0 = x0[0], mx1 = x1[0];
#pragma unroll
    for (int c = 1; c < NCLS; c++) { mx0 = fmaxf(mx0, x0[c]); mx1 = fmaxf(mx1, x1[c]); }
    float e0[NCLS], e1[NCLS];
    float s0 = 0.0f, s1 = 0.0f;
#pragma unroll
    for (int c = 0; c < NCLS; c++) {
      e0[c] = expf(x0[c] - mx0); s0 += e0[c];
      e1[c] = expf(x1[c] - mx1); s1 += e1[c];
    }
    float i0 = 1.0f / s0, i1 = 1.0f / s1;
#pragma unroll
    for (int c = 1; c < NCLS; c++) {
      unsigned k0 = __float_as_uint(e0[c] * i0) >> 16;
      unsigned k1 = __float_as_uint(e1[c] * i1) >> 16;
      skeys32[(((size_t)b * NFG + (c - 1)) * A + a) >> 1] = k0 | (k1 << 16);
    }
  }
}

// ---------------- stage 2: hist + threshold + collect + exact rescore ------
// Per (b,c) row. Pass 0: build 2048-bin hist from the skeys row (LDS
// atomics). Wave 0: shfl suffix scan -> boundary bucket t + count above.
// Pass 1 (L2-hot): collect bucket>=t as u32 (key16<<16|idx), boundary
// bucket feeds an 8-bin fine hist -> thr16 == key16 of the 200th value.
// Survivors get exact f32 recomputed from logits (identical op order as
// score_kernel => bit-identical), then rank-by-counting scatter.
__global__ __launch_bounds__(1024) void select_kernel(
    const unsigned short* __restrict__ skeys, const float* __restrict__ logits,
    int A, float* __restrict__ tval, int* __restrict__ tidx) {
  __shared__ unsigned hist[BINS];           // 8 KB
  __shared__ unsigned buf[CAP];             // 16 KB: bucket>=t candidates
  __shared__ unsigned long long fin[CAP];   // 32 KB: survivors (exact keys)
  __shared__ unsigned fineh[8];
  __shared__ int s_t, s_above, s_thr, s_cnt, s_cnt2;
  int tid = threadIdx.x;
  int row = blockIdx.x;  // b*7 + cc  (cc = class-1)
  int b = row / NFG;
  int cc = row - b * NFG;
  if (tid == 0) { s_cnt = 0; s_cnt2 = 0; }
  if (tid < 8) fineh[tid] = 0u;
  for (int i = tid; i < BINS; i += 1024) hist[i] = 0u;
  __syncthreads();

  // ---- pass 0: histogram the row (bucket = key16>>3) ----
  const uint4* p4 = (const uint4*)(skeys + (size_t)row * A);
  int n8 = A / 8;                           // 6132
  for (int k = tid; k < n8; k += 1024) {
    uint4 v = p4[k];
    unsigned wds[4] = {v.x, v.y, v.z, v.w};
#pragma unroll
    for (int w = 0; w < 4; w++) {
      atomicAdd(&hist[(wds[w] & 0xFFFFu) >> 3], 1u);
      atomicAdd(&hist[(wds[w] >> 19)], 1u);
    }
  }
  __syncthreads();

  // ---- coarse threshold: wave 0 only, shfl suffix scan ----
  if (tid < 64) {
    int lane = tid;
    const uint4* h4 = (const uint4*)hist;
    int s = 0;
#pragma unroll
    for (int k = 0; k < 8; k++) {           // 32 bins per lane
      uint4 v = h4[lane * 8 + k];
      s += (int)(v.x + v.y + v.z + v.w);
    }
    int sfx = s;                            // suffix sum over lanes >= lane
#pragma unroll
    for (int off = 1; off < 64; off <<= 1) {
      int o = __shfl(sfx, lane + off);      // wraps when OOB; masked below
      sfx += (lane + off < 64) ? o : 0;
    }
    int nxt = __shfl(sfx, lane + 1);
    nxt = (lane < 63) ? nxt : 0;
    bool mine = (sfx >= TOPK) && (nxt < TOPK);  // exactly one lane
    if (mine) {
      int cum = nxt;
      int t = lane * 32 + 31;
      for (; t >= lane * 32; t--) { cum += (int)hist[t]; if (cum >= TOPK) break; }
      s_t = t;
      s_above = cum - (int)hist[t];         // count in buckets strictly > t
    }
  }
  __syncthreads();

  // ---- pass 1 (L2-hot): bucket >= t -> buf; bucket == t -> 8-bin fine ----
  unsigned tbin = (unsigned)s_t;
  for (int k = tid; k < n8; k += 1024) {
    uint4 v = p4[k];
    unsigned wds[4] = {v.x, v.y, v.z, v.w};
#pragma unroll
    for (int w = 0; w < 4; w++) {
#pragma unroll
      for (int hf = 0; hf < 2; hf++) {
        unsigned k16 = (wds[w] >> (16 * hf)) & 0xFFFFu;
        if ((k16 >> 3) >= tbin) {
          int pos = atomicAdd(&s_cnt, 1);
          if (pos < CAP) buf[pos] = (k16 << 16) | (unsigned)(8 * k + 2 * w + hf);
          if ((k16 >> 3) == tbin) atomicAdd(&fineh[k16 & 7u], 1u);
        }
      }
    }
  }
  __syncthreads();

  // ---- fine threshold (8 sub-levels): thr16 == key16 of the 200th value ----
  if (tid == 0) {
    int need = TOPK - s_above;              // >= 1 by construction of t
    int sfx = 0, t2 = 0;
    for (int t = 7; t >= 0; t--) {
      sfx += (int)fineh[t];
      if (sfx >= need) { t2 = t; break; }
    }
    s_thr = (int)((tbin << 3) | (unsigned)t2);
  }
  __syncthreads();

  // ---- survivors: exact rescore from logits + append composite key ----
  unsigned thr = (unsigned)s_thr;
  int cnt = s_cnt; if (cnt > CAP) cnt = CAP;
  for (int i = tid; i < cnt; i += 1024) {
    unsigned v = buf[i];
    if ((v >> 16) >= thr) {
      int idx = (int)(v & 0xFFFFu);
      // recompute softmax value with IDENTICAL op order as score_kernel
      const float4* lp = (const float4*)(logits + ((size_t)b * A + idx) * NCLS);
      float4 v0 = lp[0], v1 = lp[1];
      float x[NCLS] = {v0.x, v0.y, v0.z, v0.w, v1.x, v1.y, v1.z, v1.w};
      float mx = x[0];
#pragma unroll
      for (int c = 1; c < NCLS; c++) mx = fmaxf(mx, x[c]);
      float e[NCLS];
      float s = 0.0f;
#pragma unroll
      for (int c = 0; c < NCLS; c++) { e[c] = expf(x[c] - mx); s += e[c]; }
      float inv = 1.0f / s;
      unsigned bits = __float_as_uint(e[cc + 1] * inv);
      int p = atomicAdd(&s_cnt2, 1);
      if (p < CAP)
        fin[p] = ((unsigned long long)bits << 32) | (unsigned)(~idx);
    }
  }
  __syncthreads();
  int cnt2 = s_cnt2; if (cnt2 > CAP) cnt2 = CAP;
  size_t obase = (size_t)row * TOPK;

  // rank-by-counting: composite u64 keys are unique -> ranks unique
  for (int i = tid; i < cnt2; i += 1024) {
    unsigned long long my = fin[i];
    int r = 0;
    for (int j = 0; j < cnt2; j++) r += (fin[j] > my);
    if (r < TOPK) {
      tval[obase + r] = __uint_as_float((unsigned)(my >> 32));
      tidx[obase + r] = (int)(~(unsigned)(my & 0xFFFFFFFFull));
    }
  }
  // defensive pad (unreachable unless pathological tie overflow)
  for (int r = cnt2 + tid; r < TOPK; r += 1024) {
    tval[obase + r] = 0.0f;
    tidx[obase + r] = 0;
  }
}

// ---------------- stage 3: fused gather/decode + per-image merge-rank sort --
// The 1400 candidates are 7 per-class lists, each STRICTLY DESCENDING in the
// composite key (score_bits<<32)|~m. Global sorted position = sum over the 7
// lists of count(key > key_e); own list contributes exactly r. 7 independent
// unrolled binary searches per element (ILP hides LDS latency).
__global__ __launch_bounds__(1024) void nms_sort_kernel(
    const float* __restrict__ deltas, const float* __restrict__ dbox,
    const float* __restrict__ tval, const int* __restrict__ tidx,
    float* __restrict__ cboxes, float* __restrict__ cscores,
    float* __restrict__ sx0, float* __restrict__ sy0,
    float* __restrict__ sx1, float* __restrict__ sy1,
    float* __restrict__ sar, int* __restrict__ sord, int* __restrict__ nvalid,
    int A) {
  __shared__ unsigned long long keys[NMSM];
  __shared__ float bx0[NMSM], by0[NMSM], bx1[NMSM], by1[NMSM];
  __shared__ int s_cnt;
  int tid = threadIdx.x;
  int b = blockIdx.x;
  if (tid == 0) s_cnt = 0;
  __syncthreads();

  int myv = 0;
  for (int m = tid; m < NMSM; m += 1024) {
    int c = m / TOPK;
    int r = m - c * TOPK;
    size_t tk = ((size_t)b * NFG + c) * TOPK + r;
    int a = tidx[tk];
    if (a < 0) a = 0;                       // guard padded entries
    float v = tval[tk];
    // decode
    const float* db = dbox + (size_t)a * 4;
    float w = db[2] - db[0];
    float h = db[3] - db[1];
    float cx = db[0] + 0.5f * w;
    float cy = db[1] + 0.5f * h;
    const float* dd = deltas + ((size_t)b * A + a) * 4;
    float pcx = dd[0] / 10.0f * w + cx;
    float pcy = dd[1] / 10.0f * h + cy;
    float pw = expf(dd[2] / 5.0f) * w;
    float ph = expf(dd[3] / 5.0f) * h;
    float x0 = fminf(fmaxf(pcx - 0.5f * pw, 0.0f), 1.0f);
    float y0 = fminf(fmaxf(pcy - 0.5f * ph, 0.0f), 1.0f);
    float x1 = fminf(fmaxf(pcx + 0.5f * pw, 0.0f), 1.0f);
    float y1 = fminf(fmaxf(pcy + 0.5f * ph, 0.0f), 1.0f);
    size_t gi = (size_t)b * NMSM + m;
    float* cb = cboxes + gi * 4;
    cb[0] = x0; cb[1] = y0; cb[2] = x1; cb[3] = y1;
    cscores[gi] = v;
    bx0[m] = x0; by0[m] = y0; bx1[m] = x1; by1[m] = y1;
    unsigned k32 = (v > LOW_SCORE) ? __float_as_uint(v) : 0u;
    if (k32) myv++;
    keys[m] = ((unsigned long long)k32 << 32) | (unsigned)(~m);
  }
  if (myv) atomicAdd(&s_cnt, myv);
  __syncthreads();

  size_t base = (size_t)b * NMSM;
  for (int m = tid; m < NMSM; m += 1024) {
    unsigned long long k = keys[m];
    int c = m / TOPK;
    int lo[NFG], hi[NFG];
#pragma unroll
    for (int cc = 0; cc < NFG; cc++) { lo[cc] = 0; hi[cc] = TOPK; }
#pragma unroll
    for (int s8 = 0; s8 < 8; s8++) {
#pragma unroll
      for (int cc = 0; cc < NFG; cc++) {
        if (lo[cc] < hi[cc]) {
          int mid = (lo[cc] + hi[cc]) >> 1;
          if (keys[cc * TOPK + mid] > k) lo[cc] = mid + 1; else hi[cc] = mid;
        }
      }
    }
    int p = 0;
#pragma unroll
    for (int cc = 0; cc < NFG; cc++) p += lo[cc];

    float off = 4.0f * (float)(c + 1);
    float x0 = bx0[m] + off, y0 = by0[m] + off;
    float x1 = bx1[m] + off, y1 = by1[m] + off;
    sord[base + p] = m;
    sx0[base + p] = x0; sy0[base + p] = y0;
    sx1[base + p] = x1; sy1[base + p] = y1;
    sar[base + p] = (x1 - x0) * (y1 - y0);
  }
  if (tid == 0) nvalid[b] = s_cnt;
}

// ---------------- stage 4a: suppression bitmask ----------------
// NOTE: only upper-triangle chunk pairs (cj >= ci) are WRITTEN. Words cj < ci
// of a mask row are never initialized (0xAA poison) — consumers MUST NOT
// apply them (wmask in nms_serial_kernel; this broke Round 3).
__global__ __launch_bounds__(64) void nms_mask_kernel(
    const float* __restrict__ sx0, const float* __restrict__ sy0,
    const float* __restrict__ sx1, const float* __restrict__ sy1,
    const float* __restrict__ sar, unsigned long long* __restrict__ mask) {
  int b = blockIdx.y;
  int pair = blockIdx.x;
  int ci = 0, rem = pair;
  while (rem >= NCH - ci) { rem -= NCH - ci; ci++; }
  int cj = ci + rem;   // cj >= ci (upper triangle)
  __shared__ float cx0[64], cy0[64], cx1[64], cy1[64], car[64];
  int t = threadIdx.x;
  size_t base = (size_t)b * NMSM;
  int j = cj * 64 + t;
  if (j < NMSM) {
    cx0[t] = sx0[base + j]; cy0[t] = sy0[base + j];
    cx1[t] = sx1[base + j]; cy1[t] = sy1[base + j];
    car[t] = sar[base + j];
  }
  __syncthreads();
  int i = ci * 64 + t;
  if (i >= NMSM) return;
  float x0 = sx0[base + i], y0 = sy0[base + i];
  float x1 = sx1[base + i], y1 = sy1[base + i], a = sar[base + i];
  unsigned long long bits = 0ull;
#pragma unroll 8
  for (int jj = 0; jj < 64; jj++) {
    int jg = cj * 64 + jj;
    float xl = fmaxf(x0, cx0[jj]);
    float yt = fmaxf(y0, cy0[jj]);
    float xr = fminf(x1, cx1[jj]);
    float yb = fminf(y1, cy1[jj]);
    float inter = fmaxf(xr - xl, 0.0f) * fmaxf(yb - yt, 0.0f);
    float iou = inter / (a + car[jj] - inter);
    if (jg > i && jg < NMSM && iou > NMS_THR) bits |= 1ull << jj;
  }
  mask[(base + i) * NCH + cj] = bits;
}

// ---------------- stage 4b: pipelined serial reduce + EARLY EXIT -----------
// ONE 64-lane wave per image. Per tick bi: issue DMA for block bi+2 (uniform
// LDS base), vmcnt(11) for block bi+1, consume block bi. EARLY EXIT: output
// needs only the FIRST 200 kept candidates; after committing block bi, if
// cumulative keeps >= 200, every later element's rank is >= 200 (prefix sums
// already >= 200) so their skeep words can be zeroed — break out. Typical
// data keeps most candidates -> exit after ~4 of 22 blocks. Worst case
// degenerates to the full 22.
__global__ __launch_bounds__(64) void nms_serial_kernel(
    const unsigned long long* __restrict__ mask, const int* __restrict__ sord,
    const int* __restrict__ nvalidArr,
    const float* __restrict__ cboxes, const float* __restrict__ cscores,
    float* __restrict__ out, int B) {
  __shared__ __align__(16) unsigned long long rowbuf[NBUF][BWORDS];
  __shared__ unsigned long long skeep[NCH];
  __shared__ int spfx[NCH];
  int b = blockIdx.x;
  int lane = threadIdx.x;
  int nvalid = nvalidArr[b];
  const unsigned long long* M = mask + (size_t)b * NMSM * NCH;

  // alive bit i=1 for sorted positions < nvalid
  unsigned long long remove = 0ull;
  if (lane < NCH) {
    int base = lane * 64;
    if (base + 64 <= nvalid) remove = ~0ull;
    else if (base < nvalid) remove = (~0ull) >> (64 - (nvalid - base));
  }
  bool act = (lane < NCH);
  int li = act ? lane : 0;

  auto stage = [&](int t) {
    const char* srcb = (const char*)(M + (size_t)t * BWORDS) + lane * 16;
    char* dstb = (char*)(rowbuf[t & (NBUF - 1)]);   // WAVE-UNIFORM dst
#pragma unroll
    for (int r = 0; r < NRND; r++) {
      __builtin_amdgcn_global_load_lds(
          (const __attribute__((address_space(1))) void*)(srcb + r * 1024),
          (__attribute__((address_space(3))) void*)(dstb + r * 1024),
          16, 0, 0);
    }
  };

  // prologue: blocks 0 and 1 in flight (22 outstanding)
  stage(0);
  stage(1);

  int kept = 0;
  int processed = 0;
  for (int bi = 0; bi < NCH; bi++) {
    if (bi + 2 < NCH) {
      stage(bi + 2);                                  // newest 11 in flight
      asm volatile("s_waitcnt vmcnt(11)" ::: "memory"); // block bi+1 landed
    } else {
      asm volatile("s_waitcnt vmcnt(0)" ::: "memory");  // tail: drain all
    }
    unsigned long long* rb = rowbuf[bi & (NBUF - 1)];
    // cur = alive word bi, replicated in ALL lanes (VALU chain). Diag words
    // have bits<=d clear, so decided bits are stable.
    unsigned long long cur = __shfl(remove, bi);
    unsigned long long wmask = (act && lane >= bi) ? ~0ull : 0ull;
#pragma unroll 8
    for (int d = 0; d < 64; d++) {
      unsigned long long rowd  = rb[(size_t)d * NCH + li];  // per-lane word
      unsigned long long diagd = rb[(size_t)d * NCH + bi];  // broadcast
      bool kd = (cur >> d) & 1ull;                          // uniform value
      cur    &= ~(kd ? diagd : 0ull);
      remove &= ~(kd ? (rowd & wmask) : 0ull);
    }
    remove = (lane == bi) ? cur : remove;
    kept += (int)__popcll(cur);       // cur uniform across lanes
    processed = bi + 1;
    if (kept >= TOPK) break;          // later ranks provably >= 200
  }

  // unprocessed blocks: rank >= kept >= 200 -> zero their keep words
  if (act) skeep[lane] = (lane < processed) ? remove : 0ull;
  __syncthreads();   // also drains abandoned in-flight DMA (vmcnt(0))
  if (lane == 0) {
    int s = 0;
    for (int w = 0; w < NCH; w++) { spfx[w] = s; s += __popcll(skeep[w]); }
  }
  __syncthreads();

  float* ob = out + (size_t)b * TOPK * 4;
  float* os = out + (size_t)B * TOPK * 4 + (size_t)b * TOPK;
  float* ol = out + (size_t)B * TOPK * 5 + (size_t)b * TOPK;
  for (int r = lane; r < TOPK; r += 64) {
    ob[r * 4 + 0] = 0.0f; ob[r * 4 + 1] = 0.0f;
    ob[r * 4 + 2] = 0.0f; ob[r * 4 + 3] = 0.0f;
    os[r] = 0.0f; ol[r] = 0.0f;
  }
  __syncthreads();
  size_t base = (size_t)b * NMSM;
  for (int i = lane; i < NMSM; i += 64) {
    int w = i >> 6;
    unsigned long long kw = skeep[w];
    if ((kw >> (i & 63)) & 1ull) {
      int r = spfx[w] + __popcll(kw & ((1ull << (i & 63)) - 1ull));
      if (r < TOPK) {
        int m = sord[base + i];
        const float* cb = cboxes + (base + m) * 4;
        ob[r * 4 + 0] = cb[0]; ob[r * 4 + 1] = cb[1];
        ob[r * 4 + 2] = cb[2]; ob[r * 4 + 3] = cb[3];
        os[r] = cscores[base + m];
        ol[r] = (float)(m / TOPK + 1);
      }
    }
  }
}

extern "C" void kernel_launch(void* const* d_in, const int* in_sizes, int n_in,
                              void* d_out, int out_size, void* d_ws, size_t ws_size,
                              hipStream_t stream) {
  const float* logits = (const float*)d_in[0];
  const float* deltas = (const float*)d_in[1];
  const float* dbox   = (const float*)d_in[2];
  int A = in_sizes[2] / 4;
  int B = in_sizes[0] / (A * NCLS);
  int NROWS = B * NFG;
  float* out = (float*)d_out;

  // workspace layout (no ghist anymore)
  unsigned short* skeys = (unsigned short*)d_ws;                    // B*7*A u16
  float* tval = (float*)(skeys + (size_t)B * NFG * A);              // B*7*200
  int*   tidx = (int*)(tval + (size_t)B * NFG * TOPK);              // B*7*200
  float* cboxes = (float*)(tidx + (size_t)B * NFG * TOPK);          // B*1400*4
  float* cscores = cboxes + (size_t)B * NMSM * 4;                   // B*1400

  // NMS scratch aliased onto the skeys buffer (dead after select_kernel):
  //   mask: B*1400*22 u64 = 7.885 MB at offset 0 (last image's last block
  //   stages 8 padded rows = 1.4 KB past its region — inside the 8 MB window)
  //   sorted arrays at byte offset 8 MB (within skeys' 22 MB)
  unsigned long long* mask = (unsigned long long*)d_ws;
  float* sbase = (float*)d_ws + 2097152;
  size_t n1 = (size_t)B * NMSM;
  float* sx0 = sbase;            float* sy0 = sbase + n1;
  float* sx1 = sbase + 2 * n1;   float* sy1 = sbase + 3 * n1;
  float* sar = sbase + 4 * n1;
  int*   sord = (int*)(sbase + 5 * n1);
  int*   nvalid = (int*)(sbase + 6 * n1);

  score_kernel<<<dim3(HSLICE, B), 1024, 0, stream>>>(logits, (unsigned*)skeys, A);
  select_kernel<<<NROWS, 1024, 0, stream>>>(skeys, logits, A, tval, tidx);
  nms_sort_kernel<<<B, 1024, 0, stream>>>(deltas, dbox, tval, tidx, cboxes,
                                          cscores, sx0, sy0, sx1, sy1, sar,
                                          sord, nvalid, A);
  nms_mask_kernel<<<dim3(NPAIRS, B), 64, 0, stream>>>(sx0, sy0, sx1, sy1, sar, mask);
  nms_serial_kernel<<<B, 64, 0, stream>>>(mask, sord, nvalid, cboxes, cscores, out, B);
}